// Round 3
// baseline (270.361 us; speedup 1.0000x reference)
//
#include <hip/hip_runtime.h>
#include <math.h>

#define NE 8
#define DD 1024
#define HH 2048
#define NTOK 1024
#define NSLOT 2048
#define NSLOTP 3072

typedef short short8v __attribute__((ext_vector_type(8)));
typedef short short4v __attribute__((ext_vector_type(4)));
typedef float f32x4 __attribute__((ext_vector_type(4)));

static __device__ __forceinline__ unsigned short f2bf(float f) {
  unsigned int x = __float_as_uint(f);
  return (unsigned short)((x + 0x7fffu + ((x >> 16) & 1u)) >> 16);
}

// async global->LDS, 16B per lane; LDS dst = wave-uniform base + lane*16.
#define GLD16(SRC, DST)                                                        \
  __builtin_amdgcn_global_load_lds(                                            \
      (__attribute__((address_space(1))) void*)(SRC),                          \
      (__attribute__((address_space(3))) void*)(DST), 16, 0, 0)

// B-tile row permutation for 128-row tiles: bijective; gives conflict-free
// 8B transposed writes (32 lanes, rows n=4l+c -> 32 distinct banks) and
// <=3-way ds_read_b128 fragment reads (16 consecutive rows).
static __device__ __forceinline__ int sig128(int n) {
  return (((n >> 2) ^ ((n & 3) << 3)) | ((n & 3) << 5));
}
// 64-row variant for kgemm2 B tiles.
static __device__ __forceinline__ int sig64(int n) {
  return (((n >> 2) ^ ((n & 3) << 2)) | ((n & 3) << 4));
}

// ---------------------------------------------------------------------------
// Router: one wave per token, exact f32, softmax over 8, top-2.
// ---------------------------------------------------------------------------
__global__ __launch_bounds__(64) void krouter(const float* __restrict__ x,
                                              const float* __restrict__ gw,
                                              int* __restrict__ e_sel,
                                              float* __restrict__ w_sel) {
  int n = blockIdx.x;
  int lane = threadIdx.x;
  const float4* xr = (const float4*)(x + (size_t)n * DD);
  const float4* gr = (const float4*)gw;
  float acc[NE];
#pragma unroll
  for (int e = 0; e < NE; ++e) acc[e] = 0.f;
#pragma unroll
  for (int i = 0; i < 4; ++i) {
    float4 xv = xr[lane + i * 64];
#pragma unroll
    for (int e = 0; e < NE; ++e) {
      float4 gv = gr[e * 256 + lane + i * 64];
      acc[e] += xv.x * gv.x + xv.y * gv.y + xv.z * gv.z + xv.w * gv.w;
    }
  }
#pragma unroll
  for (int e = 0; e < NE; ++e)
#pragma unroll
    for (int off = 32; off > 0; off >>= 1) acc[e] += __shfl_xor(acc[e], off);
  if (lane == 0) {
    float m = acc[0];
#pragma unroll
    for (int e = 1; e < NE; ++e) m = fmaxf(m, acc[e]);
    float p[NE];
    float z = 0.f;
#pragma unroll
    for (int e = 0; e < NE; ++e) { p[e] = expf(acc[e] - m); z += p[e]; }
    float inv = 1.f / z;
    int e1 = 0;
#pragma unroll
    for (int e = 1; e < NE; ++e) if (acc[e] > acc[e1]) e1 = e;
    int e2 = (e1 == 0) ? 1 : 0;
#pragma unroll
    for (int e = 0; e < NE; ++e) if (e != e1 && acc[e] > acc[e2]) e2 = e;
    e_sel[n] = e1;         w_sel[n] = p[e1] * inv;
    e_sel[NTOK + n] = e2;  w_sel[NTOK + n] = p[e2] * inv;
  }
}

// ---------------------------------------------------------------------------
// Build per-expert token lists, segments padded to multiples of 128.
// ---------------------------------------------------------------------------
__global__ __launch_bounds__(256) void kbuild(const int* __restrict__ e_sel,
                                              const float* __restrict__ w_sel,
                                              int* __restrict__ tok,
                                              float* __restrict__ wgt,
                                              int* __restrict__ counts,
                                              int* __restrict__ startp,
                                              int* __restrict__ nmt) {
  __shared__ int sc[NE], scur[NE];
  int t = threadIdx.x;
  if (t < NE) sc[t] = 0;
  __syncthreads();
  for (int s = t; s < NSLOTP; s += 256) tok[s] = -1;
  for (int s = t; s < NSLOT; s += 256) atomicAdd(&sc[e_sel[s]], 1);
  __syncthreads();
  if (t == 0) {
    int run = 0;
    for (int e = 0; e < NE; ++e) {
      startp[e] = run; scur[e] = run;
      counts[e] = sc[e];
      int nm = (sc[e] + 127) >> 7;
      nmt[e] = nm;
      run += nm << 7;
    }
  }
  __syncthreads();
  for (int s = t; s < NSLOT; s += 256) {
    int e = e_sel[s];
    int pos = atomicAdd(&scur[e], 1);
    tok[pos] = s & (NTOK - 1);
    wgt[pos] = w_sel[s];
  }
}

// ---------------------------------------------------------------------------
// Gather + convert x -> xg[NSLOTP][1024] bf16. Row layout: 32 chunks of 64B
// (one per K-step of BK=32); within a chunk 4 granules of 16B at position
// g ^ (row&3) so linear GLD16 staging + swizzled ds_read is conflict-free.
// Pad rows (tok==-1) zeroed.
// ---------------------------------------------------------------------------
__global__ __launch_bounds__(256) void kgather(const float* __restrict__ x,
                                               const int* __restrict__ tok,
                                               unsigned short* __restrict__ xg) {
  int row = blockIdx.x;
  int tid = threadIdx.x;
  int t = tok[row];
  // thread covers 4 f32 at k = tid*4
  int chunk = tid >> 3;                 // k>>5
  int gl = (tid >> 1) & 3;              // (k>>3)&3
  int half = tid & 1;                   // (k&7)>>2
  char* dst = (char*)xg + (size_t)row * 2048 + chunk * 64 +
              ((gl ^ (row & 3)) << 4) + half * 8;
  short4v v = {0, 0, 0, 0};
  if (t >= 0) {
    float4 f = *(const float4*)(x + (size_t)t * DD + tid * 4);
    v[0] = (short)f2bf(f.x); v[1] = (short)f2bf(f.y);
    v[2] = (short)f2bf(f.z); v[3] = (short)f2bf(f.w);
  }
  *(short4v*)dst = v;
}

// ---------------------------------------------------------------------------
// GEMM1+3 fused: h = silu(X@w1)*(X@w3). BM=128 BN=128 BK=32, 4 waves (2x2),
// wave-tile 64x64. A: xg bf16 via GLD16 (double-buffered). B: w1/w3 f32
// loaded to regs (prefetched 1 K-step ahead), reg-transposed 4x4, cvt bf16,
// written to single-buffered LDS in sig128 layout. h -> hws bf16 pre-swizzled.
// ---------------------------------------------------------------------------
__global__ __launch_bounds__(256) void kgemm13(
    const unsigned short* __restrict__ xg, const float* __restrict__ w1,
    const float* __restrict__ w3, unsigned short* __restrict__ hws,
    const int* __restrict__ counts, const int* __restrict__ startp,
    const int* __restrict__ nmt) {
  __shared__ __align__(16) char smem[16384 + 2 * 10752];
  char* ldsA = smem;                       // 2 x (128 rows x 64B)
  char* B1s = smem + 16384;                // 128 x 84B
  char* B3s = smem + 16384 + 10752;        // 128 x 84B
  int e = blockIdx.z, mt = blockIdx.y;
  if (mt >= nmt[e]) return;
  int nt = blockIdx.x, n0 = nt * 128;
  int abase = startp[e] + mt * 128;
  int tid = threadIdx.x, lane = tid & 63, w = tid >> 6;
  int wm = w & 1, wn = w >> 1;

  // ---- B staging constants (per thread) ----
  int kb = tid >> 5;            // 0..7 (k-local block of 4)
  int nb = tid & 31;            // n-local block of 4
  const size_t ew = (size_t)e * DD * HH;
  const float* pb1 = w1 + ew + (size_t)(kb * 4) * HH + n0 + nb * 4;
  const float* pb3 = w3 + ew + (size_t)(kb * 4) * HH + n0 + nb * 4;
  int boff = (kb >> 1) * 16 + (kb & 1) * 8;
  int baddr[4];
#pragma unroll
  for (int c = 0; c < 4; ++c) baddr[c] = sig128(nb * 4 + c) * 84 + boff;

  // ---- A GLD16 source constants ----
  // wave w issues 2 GLD16: rows w*32 + i*16 + (lane>>2), pos lane&3
  const char* xb = (const char*)xg;
  const char* srcA[2];
#pragma unroll
  for (int i = 0; i < 2; ++i)
    srcA[i] = xb + (size_t)(abase + w * 32 + i * 16 + (lane >> 2)) * 2048 +
              ((lane & 3) << 4);

  // ---- fragment read addresses (constant across K-steps) ----
  int aoff[4];
#pragma unroll
  for (int mf = 0; mf < 4; ++mf) {
    int r = wm * 64 + mf * 16 + (lane & 15);
    aoff[mf] = r * 64 + (((lane >> 4) ^ (r & 3)) << 4);
  }
  int b1off[4];
#pragma unroll
  for (int nf = 0; nf < 4; ++nf) {
    int n = wn * 64 + nf * 16 + (lane & 15);
    b1off[nf] = sig128(n) * 84 + ((lane >> 4) << 4);
  }

  f32x4 accg[4][4], accu[4][4];
#pragma unroll
  for (int i = 0; i < 4; ++i)
#pragma unroll
    for (int j = 0; j < 4; ++j) {
      accg[i][j] = (f32x4){0.f, 0.f, 0.f, 0.f};
      accu[i][j] = (f32x4){0.f, 0.f, 0.f, 0.f};
    }

  const int NS = DD / 32;  // 32 K-steps
  float4 p1[4], p3[4];
  // ---- prologue: stage step 0 ----
#pragma unroll
  for (int i = 0; i < 2; ++i) GLD16(srcA[i], ldsA + w * 2048 + i * 1024);
#pragma unroll
  for (int r = 0; r < 4; ++r) {
    p1[r] = *(const float4*)(pb1 + (size_t)r * HH);
    p3[r] = *(const float4*)(pb3 + (size_t)r * HH);
  }
#pragma unroll
  for (int c = 0; c < 4; ++c) {
    short4v t1, t3;
    t1[0] = (short)f2bf(p1[0][c]); t1[1] = (short)f2bf(p1[1][c]);
    t1[2] = (short)f2bf(p1[2][c]); t1[3] = (short)f2bf(p1[3][c]);
    t3[0] = (short)f2bf(p3[0][c]); t3[1] = (short)f2bf(p3[1][c]);
    t3[2] = (short)f2bf(p3[2][c]); t3[3] = (short)f2bf(p3[3][c]);
    *(short4v*)(B1s + baddr[c]) = t1;
    *(short4v*)(B3s + baddr[c]) = t3;
  }
  __syncthreads();

  int cur = 0;
  for (int s = 0; s < NS; ++s) {
    int nxt = cur ^ 1;
    // prefetch s+1: B reg-loads FIRST, then GLD16 (so cvt waits only loads)
    if (s + 1 < NS) {
      size_t ko = (size_t)(s + 1) * 32 * HH;
#pragma unroll
      for (int r = 0; r < 4; ++r) {
        p1[r] = *(const float4*)(pb1 + ko + (size_t)r * HH);
        p3[r] = *(const float4*)(pb3 + ko + (size_t)r * HH);
      }
#pragma unroll
      for (int i = 0; i < 2; ++i)
        GLD16(srcA[i] + (s + 1) * 64, ldsA + nxt * 8192 + w * 2048 + i * 1024);
    }
    // compute step s
    {
      short8v a[4], b1[4], b3[4];
#pragma unroll
      for (int mf = 0; mf < 4; ++mf)
        a[mf] = *(const short8v*)(ldsA + cur * 8192 + aoff[mf]);
#pragma unroll
      for (int nf = 0; nf < 4; ++nf) {
        b1[nf] = *(const short8v*)(B1s + b1off[nf]);
        b3[nf] = *(const short8v*)(B3s + b1off[nf]);
      }
#pragma unroll
      for (int nf = 0; nf < 4; ++nf)
#pragma unroll
        for (int mf = 0; mf < 4; ++mf) {
          accg[mf][nf] = __builtin_amdgcn_mfma_f32_16x16x32_bf16(
              a[mf], b1[nf], accg[mf][nf], 0, 0, 0);
          accu[mf][nf] = __builtin_amdgcn_mfma_f32_16x16x32_bf16(
              a[mf], b3[nf], accu[mf][nf], 0, 0, 0);
        }
    }
    asm volatile("" ::: "memory");
    __builtin_amdgcn_s_barrier();   // ldsB readers done; no vmem drain
    asm volatile("" ::: "memory");
    if (s + 1 < NS) {
#pragma unroll
      for (int c = 0; c < 4; ++c) {
        short4v t1, t3;
        t1[0] = (short)f2bf(p1[0][c]); t1[1] = (short)f2bf(p1[1][c]);
        t1[2] = (short)f2bf(p1[2][c]); t1[3] = (short)f2bf(p1[3][c]);
        t3[0] = (short)f2bf(p3[0][c]); t3[1] = (short)f2bf(p3[1][c]);
        t3[2] = (short)f2bf(p3[2][c]); t3[3] = (short)f2bf(p3[3][c]);
        *(short4v*)(B1s + baddr[c]) = t1;
        *(short4v*)(B3s + baddr[c]) = t3;
      }
    }
    __syncthreads();                // write visibility + A(s+1) landed
    cur = nxt;
  }

  // Epilogue: silu(g)*u -> bf16 -> LDS restage -> swizzled coalesced store.
  unsigned short* hl = (unsigned short*)smem;  // 128 x 128 bf16 (32KB)
#pragma unroll
  for (int mf = 0; mf < 4; ++mf)
#pragma unroll
    for (int nf = 0; nf < 4; ++nf)
#pragma unroll
      for (int rr = 0; rr < 4; ++rr) {
        int row = wm * 64 + mf * 16 + (lane >> 4) * 4 + rr;
        int col = wn * 64 + nf * 16 + (lane & 15);
        float gv = accg[mf][nf][rr], uv = accu[mf][nf][rr];
        float hv = (gv / (1.f + __expf(-gv))) * uv;
        hl[row * 128 + col] = f2bf(hv);
      }
  __syncthreads();
#pragma unroll
  for (int p = 0; p < 8; ++p) {
    int idx = p * 256 + tid;
    int row = idx >> 4, g = idx & 15;
    int dp = abase + row;
    size_t db = (size_t)dp * (HH * 2) + (size_t)n0 * 2 +
                (((g & 8) | ((g & 7) ^ (dp & 7))) << 4);
    *(short8v*)((char*)hws + db) =
        *(const short8v*)((const char*)hl + row * 256 + (g << 4));
  }
}

// ---------------------------------------------------------------------------
// GEMM2: y = h @ w2 (*routing weight), atomic scatter into out.
// BM=128 BN=64 BK=64, 4 waves (2x2), wave-tile 64x32. A: hws via GLD16
// (double-buffered). B: w2 f32 reg-prefetch + reg-transpose -> sig64 LDS.
// ---------------------------------------------------------------------------
__global__ __launch_bounds__(256) void kgemm2(
    const unsigned short* __restrict__ hws, const float* __restrict__ w2,
    float* __restrict__ out, const int* __restrict__ tok,
    const float* __restrict__ wgt, const int* __restrict__ counts,
    const int* __restrict__ startp, const int* __restrict__ nmt) {
  __shared__ __align__(16) char smem[32768 + 8448];
  char* ldsA = smem;                 // 2 x (128 rows x 128B)
  char* Bs = smem + 32768;           // 64 x 132B
  int e = blockIdx.z, mt = blockIdx.y;
  if (mt >= nmt[e]) return;
  int nt = blockIdx.x, n0 = nt * 64;
  int mbase = startp[e] + mt * 128;
  int rem = counts[e] - mt * 128;
  int tid = threadIdx.x, lane = tid & 63, w = tid >> 6;
  int wm = w & 1, wn = w >> 1;

  // ---- B staging constants ----
  int kb = tid >> 4;            // 0..15
  int nb = tid & 15;            // 0..15
  const float* pb = w2 + (size_t)e * HH * DD + (size_t)(kb * 4) * DD + n0 + nb * 4;
  int boff = (kb >> 1) * 16 + (kb & 1) * 8;
  int baddr[4];
#pragma unroll
  for (int c = 0; c < 4; ++c) baddr[c] = sig64(nb * 4 + c) * 132 + boff;

  // ---- A GLD16 sources: wave w, issue i: rows w*32+i*8+(lane>>3), pos lane&7
  const char* hb = (const char*)hws;
  const char* srcA[4];
#pragma unroll
  for (int i = 0; i < 4; ++i)
    srcA[i] = hb + (size_t)(mbase + w * 32 + i * 8 + (lane >> 3)) * 4096 +
              ((lane & 7) << 4);

  // ---- fragment read offsets ----
  int aoff[2][4];  // [ks][mf]
#pragma unroll
  for (int ks = 0; ks < 2; ++ks)
#pragma unroll
    for (int mf = 0; mf < 4; ++mf) {
      int r = wm * 64 + mf * 16 + (lane & 15);
      aoff[ks][mf] = r * 128 + (((ks * 4 + (lane >> 4)) ^ (r & 7)) << 4);
    }
  int bofr[2][2];  // [ks][nf]
#pragma unroll
  for (int ks = 0; ks < 2; ++ks)
#pragma unroll
    for (int nf = 0; nf < 2; ++nf) {
      int n = wn * 32 + nf * 16 + (lane & 15);
      bofr[ks][nf] = sig64(n) * 132 + ((ks * 4 + (lane >> 4)) << 4);
    }

  f32x4 acc[4][2];
#pragma unroll
  for (int i = 0; i < 4; ++i)
#pragma unroll
    for (int j = 0; j < 2; ++j) acc[i][j] = (f32x4){0.f, 0.f, 0.f, 0.f};

  const int NS = HH / 64;  // 32 K-steps
  float4 pB[4];
  // prologue
#pragma unroll
  for (int i = 0; i < 4; ++i) GLD16(srcA[i], ldsA + w * 4096 + i * 1024);
#pragma unroll
  for (int r = 0; r < 4; ++r) pB[r] = *(const float4*)(pb + (size_t)r * DD);
#pragma unroll
  for (int c = 0; c < 4; ++c) {
    short4v tv;
    tv[0] = (short)f2bf(pB[0][c]); tv[1] = (short)f2bf(pB[1][c]);
    tv[2] = (short)f2bf(pB[2][c]); tv[3] = (short)f2bf(pB[3][c]);
    *(short4v*)(Bs + baddr[c]) = tv;
  }
  __syncthreads();

  int cur = 0;
  for (int s = 0; s < NS; ++s) {
    int nxt = cur ^ 1;
    if (s + 1 < NS) {
      size_t ko = (size_t)(s + 1) * 64 * DD;
#pragma unroll
      for (int r = 0; r < 4; ++r)
        pB[r] = *(const float4*)(pb + ko + (size_t)r * DD);
#pragma unroll
      for (int i = 0; i < 4; ++i)
        GLD16(srcA[i] + (s + 1) * 128, ldsA + nxt * 16384 + w * 4096 + i * 1024);
    }
    {
#pragma unroll
      for (int ks = 0; ks < 2; ++ks) {
        short8v a[4], b[2];
#pragma unroll
        for (int mf = 0; mf < 4; ++mf)
          a[mf] = *(const short8v*)(ldsA + cur * 16384 + aoff[ks][mf]);
#pragma unroll
        for (int nf = 0; nf < 2; ++nf)
          b[nf] = *(const short8v*)(Bs + bofr[ks][nf]);
#pragma unroll
        for (int nf = 0; nf < 2; ++nf)
#pragma unroll
          for (int mf = 0; mf < 4; ++mf)
            acc[mf][nf] = __builtin_amdgcn_mfma_f32_16x16x32_bf16(
                a[mf], b[nf], acc[mf][nf], 0, 0, 0);
      }
    }
    asm volatile("" ::: "memory");
    __builtin_amdgcn_s_barrier();
    asm volatile("" ::: "memory");
    if (s + 1 < NS) {
#pragma unroll
      for (int c = 0; c < 4; ++c) {
        short4v tv;
        tv[0] = (short)f2bf(pB[0][c]); tv[1] = (short)f2bf(pB[1][c]);
        tv[2] = (short)f2bf(pB[2][c]); tv[3] = (short)f2bf(pB[3][c]);
        *(short4v*)(Bs + baddr[c]) = tv;
      }
    }
    __syncthreads();
    cur = nxt;
  }

#pragma unroll
  for (int mf = 0; mf < 4; ++mf)
#pragma unroll
    for (int rr = 0; rr < 4; ++rr) {
      int row = wm * 64 + mf * 16 + (lane >> 4) * 4 + rr;
      if (row < rem) {
        int t = tok[mbase + row];
        float wt = wgt[mbase + row];
        float* orow = out + (size_t)t * DD + n0;
#pragma unroll
        for (int nf = 0; nf < 2; ++nf) {
          int col = wn * 32 + nf * 16 + (lane & 15);
          atomicAdd(orow + col, wt * acc[mf][nf][rr]);
        }
      }
    }
}

// ---------------------------------------------------------------------------
extern "C" void kernel_launch(void* const* d_in, const int* in_sizes, int n_in,
                              void* d_out, int out_size, void* d_ws, size_t ws_size,
                              hipStream_t stream) {
  const float* x  = (const float*)d_in[0];
  const float* gw = (const float*)d_in[1];
  const float* w1 = (const float*)d_in[2];
  const float* w2 = (const float*)d_in[3];
  const float* w3 = (const float*)d_in[4];
  float* out = (float*)d_out;
  char* ws = (char*)d_ws;
  const size_t MB = 1024 * 1024;
  if (ws_size < 24 * MB) return;

  unsigned short* xg  = (unsigned short*)(ws);            // 3072*2048B = 6MB
  unsigned short* hws = (unsigned short*)(ws + 6 * MB);   // 3072*4096B = 12MB
  char* meta = ws + 20 * MB;
  int*   e_sel  = (int*)meta;                       // 2048
  float* w_sel  = (float*)(meta + 8192);            // 2048
  int*   tok    = (int*)(meta + 16384);             // 3072
  float* wgt    = (float*)(meta + 16384 + 12288);   // 3072
  int*   counts = (int*)(meta + 16384 + 24576);
  int*   startp = counts + 8;
  int*   nmt    = counts + 16;

  hipMemsetAsync(out, 0, (size_t)out_size * sizeof(float), stream);
  krouter<<<dim3(NTOK), 64, 0, stream>>>(x, gw, e_sel, w_sel);
  kbuild<<<1, 256, 0, stream>>>(e_sel, w_sel, tok, wgt, counts, startp, nmt);
  kgather<<<dim3(NSLOTP), 256, 0, stream>>>(x, tok, xg);
  kgemm13<<<dim3(16, 16, 8), 256, 0, stream>>>(xg, w1, w3, hws, counts,
                                               startp, nmt);
  kgemm2<<<dim3(16, 16, 8), 256, 0, stream>>>(hws, w2, out, tok, wgt, counts,
                                              startp, nmt);
}

// Round 4
// 171.169 us; speedup vs baseline: 1.5795x; 1.5795x over previous
//
#include <hip/hip_runtime.h>
#include <math.h>

#define NE 8
#define DD 1024
#define HH 2048
#define NTOK 1024
#define NSLOT 2048
#define NSLOTP 3072

typedef short short8v __attribute__((ext_vector_type(8)));
typedef short short4v __attribute__((ext_vector_type(4)));
typedef float f32x4 __attribute__((ext_vector_type(4)));

static __device__ __forceinline__ unsigned short f2bf(float f) {
  unsigned int x = __float_as_uint(f);
  return (unsigned short)((x + 0x7fffu + ((x >> 16) & 1u)) >> 16);
}

// async global->LDS, 16B/lane; LDS dst = wave-uniform base + lane*16.
#define GLD16(SRC, DST)                                                        \
  __builtin_amdgcn_global_load_lds(                                            \
      (__attribute__((address_space(1))) void*)(SRC),                          \
      (__attribute__((address_space(3))) void*)(DST), 16, 0, 0)

// ---------------------------------------------------------------------------
// Router: one wave per token, exact f32, softmax over 8, top-2.
// ---------------------------------------------------------------------------
__global__ __launch_bounds__(64) void krouter(const float* __restrict__ x,
                                              const float* __restrict__ gw,
                                              int* __restrict__ e_sel,
                                              float* __restrict__ w_sel) {
  int n = blockIdx.x;
  int lane = threadIdx.x;
  const float4* xr = (const float4*)(x + (size_t)n * DD);
  const float4* gr = (const float4*)gw;
  float acc[NE];
#pragma unroll
  for (int e = 0; e < NE; ++e) acc[e] = 0.f;
#pragma unroll
  for (int i = 0; i < 4; ++i) {
    float4 xv = xr[lane + i * 64];
#pragma unroll
    for (int e = 0; e < NE; ++e) {
      float4 gv = gr[e * 256 + lane + i * 64];
      acc[e] += xv.x * gv.x + xv.y * gv.y + xv.z * gv.z + xv.w * gv.w;
    }
  }
#pragma unroll
  for (int e = 0; e < NE; ++e)
#pragma unroll
    for (int off = 32; off > 0; off >>= 1) acc[e] += __shfl_xor(acc[e], off);
  if (lane == 0) {
    float m = acc[0];
#pragma unroll
    for (int e = 1; e < NE; ++e) m = fmaxf(m, acc[e]);
    float p[NE];
    float z = 0.f;
#pragma unroll
    for (int e = 0; e < NE; ++e) { p[e] = expf(acc[e] - m); z += p[e]; }
    float inv = 1.f / z;
    int e1 = 0;
#pragma unroll
    for (int e = 1; e < NE; ++e) if (acc[e] > acc[e1]) e1 = e;
    int e2 = (e1 == 0) ? 1 : 0;
#pragma unroll
    for (int e = 0; e < NE; ++e) if (e != e1 && acc[e] > acc[e2]) e2 = e;
    e_sel[n] = e1;         w_sel[n] = p[e1] * inv;
    e_sel[NTOK + n] = e2;  w_sel[NTOK + n] = p[e2] * inv;
  }
}

// ---------------------------------------------------------------------------
// Build per-expert token lists (segments padded to 128) + compact tile maps
// for 64-row (gemm13) and 128-row (gemm2) tiles.
// ---------------------------------------------------------------------------
__global__ __launch_bounds__(256) void kbuild(const int* __restrict__ e_sel,
                                              const float* __restrict__ w_sel,
                                              int* __restrict__ tok,
                                              float* __restrict__ wgt,
                                              int* __restrict__ meta) {
  // meta layout: [0:8) counts, [8:16) startp, [16] n64, [17] n128,
  // [32:80) t64e, [80:128) t64m, [128:152) t128e, [152:176) t128m
  __shared__ int sc[NE], scur[NE];
  int t = threadIdx.x;
  if (t < NE) sc[t] = 0;
  __syncthreads();
  for (int s = t; s < NSLOTP; s += 256) tok[s] = -1;
  for (int s = t; s < NSLOT; s += 256) atomicAdd(&sc[e_sel[s]], 1);
  __syncthreads();
  if (t == 0) {
    int run = 0, i64 = 0, i128 = 0;
    for (int e = 0; e < NE; ++e) {
      meta[8 + e] = run; scur[e] = run;
      meta[e] = sc[e];
      int nm = (sc[e] + 127) >> 7;
      for (int m = 0; m < nm; ++m) {
        meta[128 + i128] = e; meta[152 + i128] = m; ++i128;
      }
      for (int m = 0; m < 2 * nm; ++m) {
        meta[32 + i64] = e; meta[80 + i64] = m; ++i64;
      }
      run += nm << 7;
    }
    meta[16] = i64; meta[17] = i128;
  }
  __syncthreads();
  for (int s = t; s < NSLOT; s += 256) {
    int e = e_sel[s];
    int pos = atomicAdd(&scur[e], 1);
    tok[pos] = s & (NTOK - 1);
    wgt[pos] = w_sel[s];
  }
}

// ---------------------------------------------------------------------------
// Gather+convert x -> xg[NSLOTP][1024] bf16. Row = 32 chunks of 64B (one per
// BK=32 K-step); within a chunk, 16B granule g stored at g ^ ((row>>1)&3).
// Linear GLD16 staging + XOR'd ds_read = <=2-way conflicts. Pads zeroed.
// ---------------------------------------------------------------------------
__global__ __launch_bounds__(256) void kgather(const float* __restrict__ x,
                                               const int* __restrict__ tok,
                                               unsigned short* __restrict__ xg) {
  int tid = threadIdx.x;
  int row = blockIdx.x * 2 + (tid >> 7);
  int g = tid & 127;                    // 16B granule of the row (8 f32)
  int t = tok[row];
  int pos = (g & 3) ^ ((row >> 1) & 3);
  char* dst = (char*)xg + (size_t)row * 2048 + (g >> 2) * 64 + (pos << 4);
  short8v v = {0, 0, 0, 0, 0, 0, 0, 0};
  if (t >= 0) {
    const float* src = x + (size_t)t * DD + g * 8;
    float4 f0 = *(const float4*)src;
    float4 f1 = *(const float4*)(src + 4);
    v[0] = (short)f2bf(f0.x); v[1] = (short)f2bf(f0.y);
    v[2] = (short)f2bf(f0.z); v[3] = (short)f2bf(f0.w);
    v[4] = (short)f2bf(f1.x); v[5] = (short)f2bf(f1.y);
    v[6] = (short)f2bf(f1.z); v[7] = (short)f2bf(f1.w);
  }
  *(short8v*)dst = v;
}

// ---------------------------------------------------------------------------
// GEMM1+3 fused: h = silu(X@w1)*(X@w3). BM=64 BN=128 BK=32, 4 waves (1x4),
// wave-tile 64x32. A: xg via GLD16 double-buffered. B: w1/w3 f32 reg-prefetch
// one step ahead -> 4x4 reg transpose -> bf16 -> LDS [128n][64B k] with
// granule XOR ((n>>1)&3) (16B-aligned, <=2-way read conflicts).
// ---------------------------------------------------------------------------
__global__ __launch_bounds__(256, 3) void kgemm13(
    const unsigned short* __restrict__ xg, const float* __restrict__ w1,
    const float* __restrict__ w3, unsigned short* __restrict__ hws,
    const int* __restrict__ startp, const int* __restrict__ meta) {
  __shared__ __align__(16) char smem[24 * 1024];
  char* ldsA = smem;              // 2 x (64 rows x 64B) = 8KB
  char* B1s = smem + 8192;        // 128 x 64B = 8KB
  char* B3s = smem + 16384;       // 8KB
  int vt = blockIdx.y;
  if (vt >= meta[16]) return;
  int e = meta[32 + vt], mt = meta[80 + vt];
  int nt = blockIdx.x, n0 = nt * 128;
  int abase = startp[e] + mt * 64;
  int tid = threadIdx.x, lane = tid & 63, w = tid >> 6;

  // B staging map: thread covers 4n x 4k per matrix.
  int nb = tid >> 3, kb = tid & 7;
  const float* pb1 = w1 + (size_t)e * DD * HH + (size_t)(kb * 4) * HH + n0 + nb * 4;
  const float* pb3 = w3 + (size_t)e * DD * HH + (size_t)(kb * 4) * HH + n0 + nb * 4;
  int baddr[4];
#pragma unroll
  for (int c = 0; c < 4; ++c) {
    int n = nb * 4 + c;
    baddr[c] = n * 64 + (((kb >> 1) ^ ((n >> 1) & 3)) << 4) + (kb & 1) * 8;
  }
  // A GLD16 source: 1 instr/wave/step; rows w*16+(lane>>2), granule lane&3.
  const char* srcA = (const char*)xg +
                     (size_t)(abase + w * 16 + (lane >> 2)) * 2048 +
                     ((lane & 3) << 4);
  // fragment read offsets
  int aoff[4];
#pragma unroll
  for (int mf = 0; mf < 4; ++mf) {
    int r = mf * 16 + (lane & 15);
    aoff[mf] = r * 64 + (((lane >> 4) ^ ((r >> 1) & 3)) << 4);
  }
  int boff[2];
#pragma unroll
  for (int nf = 0; nf < 2; ++nf) {
    int n = w * 32 + nf * 16 + (lane & 15);
    boff[nf] = n * 64 + (((lane >> 4) ^ ((n >> 1) & 3)) << 4);
  }

  f32x4 accg[4][2], accu[4][2];
#pragma unroll
  for (int i = 0; i < 4; ++i)
#pragma unroll
    for (int j = 0; j < 2; ++j) {
      accg[i][j] = (f32x4){0.f, 0.f, 0.f, 0.f};
      accu[i][j] = (f32x4){0.f, 0.f, 0.f, 0.f};
    }

  float4 p1[4], p3[4];
  // prologue: stage step 0
  GLD16(srcA, ldsA + w * 1024);
#pragma unroll
  for (int r = 0; r < 4; ++r) {
    p1[r] = *(const float4*)(pb1 + (size_t)r * HH);
    p3[r] = *(const float4*)(pb3 + (size_t)r * HH);
  }
#pragma unroll
  for (int c = 0; c < 4; ++c) {
    short4v t1, t3;
    t1[0] = (short)f2bf(p1[0][c]); t1[1] = (short)f2bf(p1[1][c]);
    t1[2] = (short)f2bf(p1[2][c]); t1[3] = (short)f2bf(p1[3][c]);
    t3[0] = (short)f2bf(p3[0][c]); t3[1] = (short)f2bf(p3[1][c]);
    t3[2] = (short)f2bf(p3[2][c]); t3[3] = (short)f2bf(p3[3][c]);
    *(short4v*)(B1s + baddr[c]) = t1;
    *(short4v*)(B3s + baddr[c]) = t3;
  }
  __syncthreads();

  int cur = 0;
  const int NS = 32;
  for (int s = 0; s < NS; ++s) {
    if (s + 1 < NS) {
      size_t ko = (size_t)(s + 1) * 32 * HH;
#pragma unroll
      for (int r = 0; r < 4; ++r) {
        p1[r] = *(const float4*)(pb1 + ko + (size_t)r * HH);
        p3[r] = *(const float4*)(pb3 + ko + (size_t)r * HH);
      }
      GLD16(srcA + (s + 1) * 64, ldsA + (cur ^ 1) * 4096 + w * 1024);
    }
    {
      short8v a[4], b1[2], b3[2];
#pragma unroll
      for (int mf = 0; mf < 4; ++mf)
        a[mf] = *(const short8v*)(ldsA + cur * 4096 + aoff[mf]);
#pragma unroll
      for (int nf = 0; nf < 2; ++nf) {
        b1[nf] = *(const short8v*)(B1s + boff[nf]);
        b3[nf] = *(const short8v*)(B3s + boff[nf]);
      }
#pragma unroll
      for (int nf = 0; nf < 2; ++nf)
#pragma unroll
        for (int mf = 0; mf < 4; ++mf) {
          accg[mf][nf] = __builtin_amdgcn_mfma_f32_16x16x32_bf16(
              a[mf], b1[nf], accg[mf][nf], 0, 0, 0);
          accu[mf][nf] = __builtin_amdgcn_mfma_f32_16x16x32_bf16(
              a[mf], b3[nf], accu[mf][nf], 0, 0, 0);
        }
    }
    asm volatile("" ::: "memory");
    __builtin_amdgcn_s_barrier();   // B readers done; no vmem drain
    asm volatile("" ::: "memory");
    if (s + 1 < NS) {
#pragma unroll
      for (int c = 0; c < 4; ++c) {
        short4v t1, t3;
        t1[0] = (short)f2bf(p1[0][c]); t1[1] = (short)f2bf(p1[1][c]);
        t1[2] = (short)f2bf(p1[2][c]); t1[3] = (short)f2bf(p1[3][c]);
        t3[0] = (short)f2bf(p3[0][c]); t3[1] = (short)f2bf(p3[1][c]);
        t3[2] = (short)f2bf(p3[2][c]); t3[3] = (short)f2bf(p3[3][c]);
        *(short4v*)(B1s + baddr[c]) = t1;
        *(short4v*)(B3s + baddr[c]) = t3;
      }
    }
    __syncthreads();                // B writes visible + A(s+1) landed
    cur ^= 1;
  }

  // Epilogue: silu(g)*u -> bf16 -> LDS restage -> swizzled 16B stores to hws.
  unsigned short* hl = (unsigned short*)smem;  // 64 x 128 bf16 = 16KB
#pragma unroll
  for (int mf = 0; mf < 4; ++mf)
#pragma unroll
    for (int nf = 0; nf < 2; ++nf)
#pragma unroll
      for (int rr = 0; rr < 4; ++rr) {
        int row = mf * 16 + (lane >> 4) * 4 + rr;
        int col = w * 32 + nf * 16 + (lane & 15);
        float gv = accg[mf][nf][rr], uv = accu[mf][nf][rr];
        float hv = (gv / (1.f + __expf(-gv))) * uv;
        hl[row * 128 + col] = f2bf(hv);
      }
  __syncthreads();
#pragma unroll
  for (int p = 0; p < 4; ++p) {
    int idx = p * 256 + tid;
    int row = idx >> 4, g = idx & 15;
    int dp = abase + row;
    size_t db = (size_t)dp * 4096 + (size_t)n0 * 2 + ((g >> 3) << 7) +
                (((g & 7) ^ (dp & 7)) << 4);
    *(short8v*)((char*)hws + db) =
        *(const short8v*)((const char*)hl + row * 256 + (g << 4));
  }
}

// ---------------------------------------------------------------------------
// GEMM2: y = h @ w2 (*routing weight), atomic scatter into out. K-split 2.
// BM=128 BN=64 BK=64, 4 waves (2x2), wave-tile 64x32. A: hws via GLD16
// double-buffered. B: w2 f32 reg-prefetch -> reg transpose -> LDS
// [64n][128B k] granule XOR (n&7).
// ---------------------------------------------------------------------------
__global__ __launch_bounds__(256, 4) void kgemm2(
    const unsigned short* __restrict__ hws, const float* __restrict__ w2,
    float* __restrict__ out, const int* __restrict__ tok,
    const float* __restrict__ wgt, const int* __restrict__ counts,
    const int* __restrict__ startp, const int* __restrict__ meta) {
  __shared__ __align__(16) char smem[40 * 1024];
  char* ldsA = smem;              // 2 x (128 rows x 128B) = 32KB
  char* Bs = smem + 32768;        // 64 x 128B = 8KB
  int vt = blockIdx.y;
  if (vt >= meta[17]) return;
  int e = meta[128 + vt], mt = meta[152 + vt];
  int nt = blockIdx.x, n0 = nt * 64;
  int kz = blockIdx.z;            // K half: [kz*1024, kz*1024+1024)
  int mbase = startp[e] + mt * 128;
  int rem = counts[e] - mt * 128;
  int tid = threadIdx.x, lane = tid & 63, w = tid >> 6;
  int wm = w & 1, wn = w >> 1;

  // B staging: thread covers 4n x 4k.
  int nb = tid >> 4, kb = tid & 15;
  const float* pb = w2 + (size_t)e * HH * DD +
                    (size_t)(kz * 1024 + kb * 4) * DD + n0 + nb * 4;
  int baddr[4];
#pragma unroll
  for (int c = 0; c < 4; ++c) {
    int n = nb * 4 + c;
    baddr[c] = n * 128 + (((kb >> 1) ^ (n & 7)) << 4) + (kb & 1) * 8;
  }
  // A GLD16: 4 instrs/wave/step; rows w*32+i*8+(lane>>3), granule lane&7.
  const char* srcA[4];
#pragma unroll
  for (int i = 0; i < 4; ++i)
    srcA[i] = (const char*)hws +
              (size_t)(mbase + w * 32 + i * 8 + (lane >> 3)) * 4096 +
              (size_t)kz * 2048 + ((lane & 7) << 4);
  // fragment read offsets
  int aoff[2][4], boff[2][2];
#pragma unroll
  for (int ks = 0; ks < 2; ++ks) {
#pragma unroll
    for (int mf = 0; mf < 4; ++mf) {
      int r = wm * 64 + mf * 16 + (lane & 15);
      aoff[ks][mf] = r * 128 + (((ks * 4 + (lane >> 4)) ^ (r & 7)) << 4);
    }
#pragma unroll
    for (int nf = 0; nf < 2; ++nf) {
      int n = wn * 32 + nf * 16 + (lane & 15);
      boff[ks][nf] = n * 128 + (((ks * 4 + (lane >> 4)) ^ (n & 7)) << 4);
    }
  }

  f32x4 acc[4][2];
#pragma unroll
  for (int i = 0; i < 4; ++i)
#pragma unroll
    for (int j = 0; j < 2; ++j) acc[i][j] = (f32x4){0.f, 0.f, 0.f, 0.f};

  float4 pB[4];
  // prologue
#pragma unroll
  for (int i = 0; i < 4; ++i) GLD16(srcA[i], ldsA + w * 4096 + i * 1024);
#pragma unroll
  for (int r = 0; r < 4; ++r) pB[r] = *(const float4*)(pb + (size_t)r * DD);
#pragma unroll
  for (int c = 0; c < 4; ++c) {
    short4v tv;
    tv[0] = (short)f2bf(pB[0][c]); tv[1] = (short)f2bf(pB[1][c]);
    tv[2] = (short)f2bf(pB[2][c]); tv[3] = (short)f2bf(pB[3][c]);
    *(short4v*)(Bs + baddr[c]) = tv;
  }
  __syncthreads();

  int cur = 0;
  const int NS = 16;
  for (int s = 0; s < NS; ++s) {
    if (s + 1 < NS) {
      size_t ko = (size_t)(s + 1) * 64 * DD;
#pragma unroll
      for (int r = 0; r < 4; ++r)
        pB[r] = *(const float4*)(pb + ko + (size_t)r * DD);
#pragma unroll
      for (int i = 0; i < 4; ++i)
        GLD16(srcA[i] + (s + 1) * 128,
              ldsA + (cur ^ 1) * 16384 + w * 4096 + i * 1024);
    }
#pragma unroll
    for (int ks = 0; ks < 2; ++ks) {
      short8v a[4], b[2];
#pragma unroll
      for (int mf = 0; mf < 4; ++mf)
        a[mf] = *(const short8v*)(ldsA + cur * 16384 + aoff[ks][mf]);
#pragma unroll
      for (int nf = 0; nf < 2; ++nf)
        b[nf] = *(const short8v*)(Bs + boff[ks][nf]);
#pragma unroll
      for (int nf = 0; nf < 2; ++nf)
#pragma unroll
        for (int mf = 0; mf < 4; ++mf)
          acc[mf][nf] = __builtin_amdgcn_mfma_f32_16x16x32_bf16(
              a[mf], b[nf], acc[mf][nf], 0, 0, 0);
    }
    asm volatile("" ::: "memory");
    __builtin_amdgcn_s_barrier();
    asm volatile("" ::: "memory");
    if (s + 1 < NS) {
#pragma unroll
      for (int c = 0; c < 4; ++c) {
        short4v tv;
        tv[0] = (short)f2bf(pB[0][c]); tv[1] = (short)f2bf(pB[1][c]);
        tv[2] = (short)f2bf(pB[2][c]); tv[3] = (short)f2bf(pB[3][c]);
        *(short4v*)(Bs + baddr[c]) = tv;
      }
    }
    __syncthreads();
    cur ^= 1;
  }

#pragma unroll
  for (int mf = 0; mf < 4; ++mf)
#pragma unroll
    for (int rr = 0; rr < 4; ++rr) {
      int row = wm * 64 + mf * 16 + (lane >> 4) * 4 + rr;
      if (row < rem) {
        int t = tok[mbase + row];
        float wt = wgt[mbase + row];
        float* orow = out + (size_t)t * DD + n0;
#pragma unroll
        for (int nf = 0; nf < 2; ++nf) {
          int col = wn * 32 + nf * 16 + (lane & 15);
          atomicAdd(orow + col, wt * acc[mf][nf][rr]);
        }
      }
    }
}

// ---------------------------------------------------------------------------
extern "C" void kernel_launch(void* const* d_in, const int* in_sizes, int n_in,
                              void* d_out, int out_size, void* d_ws, size_t ws_size,
                              hipStream_t stream) {
  const float* x  = (const float*)d_in[0];
  const float* gw = (const float*)d_in[1];
  const float* w1 = (const float*)d_in[2];
  const float* w2 = (const float*)d_in[3];
  const float* w3 = (const float*)d_in[4];
  float* out = (float*)d_out;
  char* ws = (char*)d_ws;
  const size_t MB = 1024 * 1024;
  if (ws_size < 24 * MB) return;

  unsigned short* xg  = (unsigned short*)(ws);            // 3072*2048B = 6MB
  unsigned short* hws = (unsigned short*)(ws + 6 * MB);   // 3072*4096B = 12MB
  char* mb = ws + 20 * MB;
  int*   e_sel  = (int*)mb;                       // 2048
  float* w_sel  = (float*)(mb + 8192);            // 2048
  int*   tok    = (int*)(mb + 16384);             // 3072
  float* wgt    = (float*)(mb + 16384 + 12288);   // 3072
  int*   meta   = (int*)(mb + 16384 + 24576);     // 256 ints
  int*   counts = meta;
  int*   startp = meta + 8;

  hipMemsetAsync(out, 0, (size_t)out_size * sizeof(float), stream);
  krouter<<<dim3(NTOK), 64, 0, stream>>>(x, gw, e_sel, w_sel);
  kbuild<<<1, 256, 0, stream>>>(e_sel, w_sel, tok, wgt, meta);
  kgather<<<dim3(NSLOTP / 2), 256, 0, stream>>>(x, tok, xg);
  kgemm13<<<dim3(16, 48), 256, 0, stream>>>(xg, w1, w3, hws, startp, meta);
  kgemm2<<<dim3(16, 24, 2), 256, 0, stream>>>(hws, w2, out, tok, wgt, counts,
                                              startp, meta);
}

// Round 6
// 119.584 us; speedup vs baseline: 2.2608x; 1.4314x over previous
//
#include <hip/hip_runtime.h>
#include <hip/hip_bf16.h>
#include <math.h>

#define NE 8
#define DD 1024
#define HH 2048
#define NTOK 1024
#define NSLOT 2048
#define NSLOTP 3072

typedef short short8v __attribute__((ext_vector_type(8)));
typedef short short4v __attribute__((ext_vector_type(4)));
typedef float f32x4 __attribute__((ext_vector_type(4)));

static __device__ __forceinline__ unsigned short f2bf(float f) {
  union { __hip_bfloat16 h; unsigned short u; } c;
  c.h = __float2bfloat16(f);
  return c.u;
}

// bank-spread for bf16 [n][64B k-row] tiles: granule position = g ^ sigma(n)
static __device__ __forceinline__ int sigma(int n) {
  return ((n >> 1) & 3) ^ ((n >> 3) & 1);
}

// async global->LDS, 16B/lane; LDS dst = wave-uniform base (HW adds lane*16).
#define GLD16(SRC, DST)                                                        \
  __builtin_amdgcn_global_load_lds(                                            \
      (__attribute__((address_space(1))) void*)(SRC),                          \
      (__attribute__((address_space(3))) void*)(DST), 16, 0, 0)

// ---------------------------------------------------------------------------
// Router: one wave per token, exact f32, softmax over 8, top-2.
// ---------------------------------------------------------------------------
__global__ __launch_bounds__(64) void krouter(const float* __restrict__ x,
                                              const float* __restrict__ gw,
                                              int* __restrict__ e_sel,
                                              float* __restrict__ w_sel) {
  int n = blockIdx.x;
  int lane = threadIdx.x;
  const float4* xr = (const float4*)(x + (size_t)n * DD);
  const float4* gr = (const float4*)gw;
  float acc[NE];
#pragma unroll
  for (int e = 0; e < NE; ++e) acc[e] = 0.f;
#pragma unroll
  for (int i = 0; i < 4; ++i) {
    float4 xv = xr[lane + i * 64];
#pragma unroll
    for (int e = 0; e < NE; ++e) {
      float4 gv = gr[e * 256 + lane + i * 64];
      acc[e] += xv.x * gv.x + xv.y * gv.y + xv.z * gv.z + xv.w * gv.w;
    }
  }
#pragma unroll
  for (int e = 0; e < NE; ++e)
#pragma unroll
    for (int off = 32; off > 0; off >>= 1) acc[e] += __shfl_xor(acc[e], off);
  if (lane == 0) {
    float m = acc[0];
#pragma unroll
    for (int e = 1; e < NE; ++e) m = fmaxf(m, acc[e]);
    float p[NE];
    float z = 0.f;
#pragma unroll
    for (int e = 0; e < NE; ++e) { p[e] = expf(acc[e] - m); z += p[e]; }
    float inv = 1.f / z;
    int e1 = 0;
#pragma unroll
    for (int e = 1; e < NE; ++e) if (acc[e] > acc[e1]) e1 = e;
    int e2 = (e1 == 0) ? 1 : 0;
#pragma unroll
    for (int e = 0; e < NE; ++e) if (e != e1 && acc[e] > acc[e2]) e2 = e;
    e_sel[n] = e1;         w_sel[n] = p[e1] * inv;
    e_sel[NTOK + n] = e2;  w_sel[NTOK + n] = p[e2] * inv;
  }
}

// ---------------------------------------------------------------------------
// Build per-expert token lists (segments padded to 128) + compact tile maps.
// meta: [0:8) counts, [8:16) startp, [16] n64, [17] n128,
//       [32:80) t64e, [80:128) t64m, [128:152) t128e, [152:176) t128m
// ---------------------------------------------------------------------------
__global__ __launch_bounds__(256) void kbuild(const int* __restrict__ e_sel,
                                              const float* __restrict__ w_sel,
                                              int* __restrict__ tok,
                                              float* __restrict__ wgt,
                                              int* __restrict__ meta) {
  __shared__ int sc[NE], scur[NE];
  int t = threadIdx.x;
  if (t < NE) sc[t] = 0;
  __syncthreads();
  for (int s = t; s < NSLOTP; s += 256) tok[s] = -1;
  for (int s = t; s < NSLOT; s += 256) atomicAdd(&sc[e_sel[s]], 1);
  __syncthreads();
  if (t == 0) {
    int run = 0, i64 = 0, i128 = 0;
    for (int e = 0; e < NE; ++e) {
      meta[8 + e] = run; scur[e] = run;
      meta[e] = sc[e];
      int nm = (sc[e] + 127) >> 7;
      for (int m = 0; m < nm; ++m) {
        meta[128 + i128] = e; meta[152 + i128] = m; ++i128;
      }
      for (int m = 0; m < 2 * nm; ++m) {
        meta[32 + i64] = e; meta[80 + i64] = m; ++i64;
      }
      run += nm << 7;
    }
    meta[16] = i64; meta[17] = i128;
  }
  __syncthreads();
  for (int s = t; s < NSLOT; s += 256) {
    int e = e_sel[s];
    int pos = atomicAdd(&scur[e], 1);
    tok[pos] = s & (NTOK - 1);
    wgt[pos] = w_sel[s];
  }
}

// ---------------------------------------------------------------------------
// Gather+convert x -> xg[NSLOTP][1024] bf16. Row = 32 chunks of 64B; within a
// chunk, granule g stored at g ^ ((row>>1)&3). Linear GLD16 staging + XOR'd
// ds_read_b128 is conflict-light. Pad rows zeroed. [verified r4]
// ---------------------------------------------------------------------------
__global__ __launch_bounds__(256) void kgather(const float* __restrict__ x,
                                               const int* __restrict__ tok,
                                               unsigned short* __restrict__ xg) {
  int tid = threadIdx.x;
  int row = blockIdx.x * 2 + (tid >> 7);
  int g = tid & 127;
  int t = tok[row];
  int pos = (g & 3) ^ ((row >> 1) & 3);
  char* dst = (char*)xg + (size_t)row * 2048 + (g >> 2) * 64 + (pos << 4);
  short8v v = {0, 0, 0, 0, 0, 0, 0, 0};
  if (t >= 0) {
    const float* src = x + (size_t)t * DD + g * 8;
    float4 f0 = *(const float4*)src;
    float4 f1 = *(const float4*)(src + 4);
    v[0] = (short)f2bf(f0.x); v[1] = (short)f2bf(f0.y);
    v[2] = (short)f2bf(f0.z); v[3] = (short)f2bf(f0.w);
    v[4] = (short)f2bf(f1.x); v[5] = (short)f2bf(f1.y);
    v[6] = (short)f2bf(f1.z); v[7] = (short)f2bf(f1.w);
  }
  *(short8v*)dst = v;
}

// ---------------------------------------------------------------------------
// GEMM1+3 fused: h = silu(X@w1)*(X@w3). BM=64 BN=64 BK=32, 4 waves n-split
// (wave-tile 64x16). A: xg via GLD16, double-buffered. B: w1/w3 f32 loaded
// coalesced to regs (2-step pipeline), cvt bf16, transposed ds_write into
// double-buffered [n][64B] tiles with sigma() granule swizzle.
// ---------------------------------------------------------------------------
__global__ __launch_bounds__(256, 4) void kgemm13(
    const unsigned short* __restrict__ xg, const float* __restrict__ w1,
    const float* __restrict__ w3, unsigned short* __restrict__ hws,
    const int* __restrict__ meta) {
  __shared__ __align__(16) char smem[24576];
  char* ldsA = smem;             // 2 buf x 4KB (64 rows x 64B)
  char* ldsB = smem + 8192;      // 2 buf x 2 mat x 4KB (64 n x 64B)
  int vt = blockIdx.y;
  if (vt >= meta[16]) return;
  int e = meta[32 + vt], mt = meta[80 + vt];
  int n0 = blockIdx.x * 64;
  int abase = meta[8 + e] + mt * 64;
  int tid = threadIdx.x, l = tid & 63, w = tid >> 6;

  // B staging: threads 0-127 -> w1, 128-255 -> w3; thread covers 4k x 4n.
  int th = tid & 127;
  int nb = th & 15, kb = th >> 4;        // n = 4nb (coalesced), k = 4kb
  const float* wsrc = (tid < 128) ? w1 : w3;
  const float* pb = wsrc + (size_t)e * DD * HH + (size_t)(kb * 4) * HH + n0 + nb * 4;
  int mofs = (tid < 128) ? 0 : 4096;
  int baddr[4];
#pragma unroll
  for (int c = 0; c < 4; ++c) {
    int n = nb * 4 + c;
    baddr[c] = mofs + n * 64 + ((((kb >> 1) ^ sigma(n)) & 3) << 4) + (kb & 1) * 8;
  }
  // A staging: 1 GLD16/wave: rows w*16+(l>>2), granule l&3 (verbatim xg copy)
  const char* srcA = (const char*)xg +
                     (size_t)(abase + w * 16 + (l >> 2)) * 2048 + ((l & 3) << 4);
  // fragment read offsets
  int aoff[4];
#pragma unroll
  for (int mf = 0; mf < 4; ++mf) {
    int r = mf * 16 + (l & 15);
    aoff[mf] = r * 64 + ((((l >> 4) ^ (r >> 1)) & 3) << 4);
  }
  int nn = w * 16 + (l & 15);
  int boff = nn * 64 + ((((l >> 4) ^ sigma(nn)) & 3) << 4);

  f32x4 accg[4], accu[4];
#pragma unroll
  for (int i = 0; i < 4; ++i) {
    accg[i] = (f32x4){0.f, 0.f, 0.f, 0.f};
    accu[i] = (f32x4){0.f, 0.f, 0.f, 0.f};
  }

  float4 q[4];
  const float* qp = pb;
  // ---- prologue: stage steps 0 and 1 ----
#pragma unroll
  for (int r = 0; r < 4; ++r) q[r] = *(const float4*)(qp + (size_t)r * HH);
  GLD16(srcA, ldsA + w * 1024);
#pragma unroll
  for (int c = 0; c < 4; ++c) {
    short4v tv;
    tv[0] = (short)f2bf(q[0][c]); tv[1] = (short)f2bf(q[1][c]);
    tv[2] = (short)f2bf(q[2][c]); tv[3] = (short)f2bf(q[3][c]);
    *(short4v*)(ldsB + baddr[c]) = tv;
  }
  qp += 32 * HH;
#pragma unroll
  for (int r = 0; r < 4; ++r) q[r] = *(const float4*)(qp + (size_t)r * HH);
  GLD16(srcA + 64, ldsA + 4096 + w * 1024);
  qp += 32 * HH;
  __syncthreads();

  for (int s = 0; s < 32; ++s) {
    int buf = s & 1;
    // compute(s)
    short8v a[4];
#pragma unroll
    for (int mf = 0; mf < 4; ++mf)
      a[mf] = *(const short8v*)(ldsA + buf * 4096 + aoff[mf]);
    short8v bg = *(const short8v*)(ldsB + buf * 8192 + boff);
    short8v bu = *(const short8v*)(ldsB + buf * 8192 + 4096 + boff);
#pragma unroll
    for (int mf = 0; mf < 4; ++mf) {
      accg[mf] = __builtin_amdgcn_mfma_f32_16x16x32_bf16(a[mf], bg, accg[mf], 0, 0, 0);
      accu[mf] = __builtin_amdgcn_mfma_f32_16x16x32_bf16(a[mf], bu, accu[mf], 0, 0, 0);
    }
    // write B(s+1) into other buffer (waits only q(s+1), one step of slack)
    if (s < 31) {
      char* d = ldsB + (buf ^ 1) * 8192;
#pragma unroll
      for (int c = 0; c < 4; ++c) {
        short4v tv;
        tv[0] = (short)f2bf(q[0][c]); tv[1] = (short)f2bf(q[1][c]);
        tv[2] = (short)f2bf(q[2][c]); tv[3] = (short)f2bf(q[3][c]);
        *(short4v*)(d + baddr[c]) = tv;
      }
    }
    __syncthreads();  // drains A(s+1) GLD16; B(s+1) visible
    // issue loads for step s+2
    if (s < 30) {
#pragma unroll
      for (int r = 0; r < 4; ++r) q[r] = *(const float4*)(qp + (size_t)r * HH);
      GLD16(srcA + (s + 2) * 64, ldsA + buf * 4096 + w * 1024);
      qp += 32 * HH;
    }
  }

  // Epilogue: silu(g)*u -> bf16 -> LDS restage -> xg-format store to hws.
  unsigned short* hl = (unsigned short*)smem;  // 64 x 64 bf16 = 8KB
#pragma unroll
  for (int mf = 0; mf < 4; ++mf)
#pragma unroll
    for (int rr = 0; rr < 4; ++rr) {
      int row = mf * 16 + ((l >> 4) << 2) + rr;
      int col = w * 16 + (l & 15);
      float gv = accg[mf][rr], uv = accu[mf][rr];
      hl[row * 64 + col] = f2bf((gv / (1.f + __expf(-gv))) * uv);
    }
  __syncthreads();
#pragma unroll
  for (int p = 0; p < 2; ++p) {
    int idx = p * 256 + tid;
    int row = idx >> 3, g = idx & 7;
    int dp = abase + row;
    size_t db = (size_t)dp * 4096 + (size_t)n0 * 2 + (g >> 2) * 64 +
                ((size_t)((g & 3) ^ ((dp >> 1) & 3)) << 4);
    *(short8v*)((char*)hws + db) =
        *(const short8v*)((const char*)hl + row * 128 + (g << 4));
  }
}

// ---------------------------------------------------------------------------
// GEMM2: y = h @ w2 (*routing weight), atomic scatter. BM=64 BN=64 BK=32,
// K-split 2, 4 waves n-split. Same pipeline as kgemm13, one B matrix.
// ---------------------------------------------------------------------------
__global__ __launch_bounds__(256, 4) void kgemm2(
    const unsigned short* __restrict__ hws, const float* __restrict__ w2,
    float* __restrict__ out, const int* __restrict__ tok,
    const float* __restrict__ wgt, const int* __restrict__ meta) {
  __shared__ __align__(16) char smem[16384];
  char* ldsA = smem;             // 2 buf x 4KB
  char* ldsB = smem + 8192;      // 2 buf x 4KB (64 n x 64B)
  int vt = blockIdx.y;
  if (vt >= meta[16]) return;
  int e = meta[32 + vt], mt = meta[80 + vt];
  int n0 = blockIdx.x * 64;
  int kz = blockIdx.z;
  int mbase = meta[8 + e] + mt * 64;
  int rem = meta[e] - mt * 64;
  int tid = threadIdx.x, l = tid & 63, w = tid >> 6;

  // B staging: thread covers 2k x 4n (coalesced n).
  int nb = tid & 15, kb = tid >> 4;     // n = 4nb, k = 2kb (0..30)
  const float* pb = w2 + (size_t)e * HH * DD +
                    (size_t)(kz * 1024 + kb * 2) * DD + n0 + nb * 4;
  int baddr[4];
#pragma unroll
  for (int c = 0; c < 4; ++c) {
    int n = nb * 4 + c;
    baddr[c] = n * 64 + ((((kb >> 2) ^ sigma(n)) & 3) << 4) + (kb & 3) * 4;
  }
  const char* srcA = (const char*)hws +
                     (size_t)(mbase + w * 16 + (l >> 2)) * 4096 +
                     (size_t)kz * 2048 + ((l & 3) << 4);
  int aoff[4];
#pragma unroll
  for (int mf = 0; mf < 4; ++mf) {
    int r = mf * 16 + (l & 15);
    aoff[mf] = r * 64 + ((((l >> 4) ^ (r >> 1)) & 3) << 4);
  }
  int nn = w * 16 + (l & 15);
  int boff = nn * 64 + ((((l >> 4) ^ sigma(nn)) & 3) << 4);

  f32x4 acc[4];
#pragma unroll
  for (int i = 0; i < 4; ++i) acc[i] = (f32x4){0.f, 0.f, 0.f, 0.f};

  float4 q[2];
  const float* qp = pb;
#pragma unroll
  for (int r = 0; r < 2; ++r) q[r] = *(const float4*)(qp + (size_t)r * DD);
  GLD16(srcA, ldsA + w * 1024);
  {
#pragma unroll
    for (int c = 0; c < 4; ++c) {
      unsigned v = (unsigned)f2bf(q[0][c]) | ((unsigned)f2bf(q[1][c]) << 16);
      *(unsigned*)(ldsB + baddr[c]) = v;
    }
  }
  qp += 32 * DD;
#pragma unroll
  for (int r = 0; r < 2; ++r) q[r] = *(const float4*)(qp + (size_t)r * DD);
  GLD16(srcA + 64, ldsA + 4096 + w * 1024);
  qp += 32 * DD;
  __syncthreads();

  for (int s = 0; s < 32; ++s) {
    int buf = s & 1;
    short8v a[4];
#pragma unroll
    for (int mf = 0; mf < 4; ++mf)
      a[mf] = *(const short8v*)(ldsA + buf * 4096 + aoff[mf]);
    short8v b = *(const short8v*)(ldsB + buf * 4096 + boff);
#pragma unroll
    for (int mf = 0; mf < 4; ++mf)
      acc[mf] = __builtin_amdgcn_mfma_f32_16x16x32_bf16(a[mf], b, acc[mf], 0, 0, 0);
    if (s < 31) {
      char* d = ldsB + (buf ^ 1) * 4096;
#pragma unroll
      for (int c = 0; c < 4; ++c) {
        unsigned v = (unsigned)f2bf(q[0][c]) | ((unsigned)f2bf(q[1][c]) << 16);
        *(unsigned*)(d + baddr[c]) = v;
      }
    }
    __syncthreads();
    if (s < 30) {
#pragma unroll
      for (int r = 0; r < 2; ++r) q[r] = *(const float4*)(qp + (size_t)r * DD);
      GLD16(srcA + (s + 2) * 64, ldsA + buf * 4096 + w * 1024);
      qp += 32 * DD;
    }
  }

#pragma unroll
  for (int mf = 0; mf < 4; ++mf)
#pragma unroll
    for (int rr = 0; rr < 4; ++rr) {
      int row = mf * 16 + ((l >> 4) << 2) + rr;
      if (row < rem) {
        int t = tok[mbase + row];
        float wt = wgt[mbase + row];
        atomicAdd(out + (size_t)t * DD + n0 + w * 16 + (l & 15),
                  wt * acc[mf][rr]);
      }
    }
}

// ---------------------------------------------------------------------------
extern "C" void kernel_launch(void* const* d_in, const int* in_sizes, int n_in,
                              void* d_out, int out_size, void* d_ws, size_t ws_size,
                              hipStream_t stream) {
  const float* x  = (const float*)d_in[0];
  const float* gw = (const float*)d_in[1];
  const float* w1 = (const float*)d_in[2];
  const float* w2 = (const float*)d_in[3];
  const float* w3 = (const float*)d_in[4];
  float* out = (float*)d_out;
  char* ws = (char*)d_ws;
  const size_t MB = 1024 * 1024;
  if (ws_size < 24 * MB) return;

  unsigned short* xg  = (unsigned short*)(ws);            // 6MB
  unsigned short* hws = (unsigned short*)(ws + 6 * MB);   // 12MB
  char* mb = ws + 20 * MB;
  int*   e_sel  = (int*)mb;
  float* w_sel  = (float*)(mb + 8192);
  int*   tok    = (int*)(mb + 16384);
  float* wgt    = (float*)(mb + 16384 + 12288);
  int*   meta   = (int*)(mb + 16384 + 24576);

  hipMemsetAsync(out, 0, (size_t)out_size * sizeof(float), stream);
  krouter<<<dim3(NTOK), 64, 0, stream>>>(x, gw, e_sel, w_sel);
  kbuild<<<1, 256, 0, stream>>>(e_sel, w_sel, tok, wgt, meta);
  kgather<<<dim3(NSLOTP / 2), 256, 0, stream>>>(x, tok, xg);
  kgemm13<<<dim3(32, 48), 256, 0, stream>>>(xg, w1, w3, hws, meta);
  kgemm2<<<dim3(16, 48, 2), 256, 0, stream>>>(hws, w2, out, tok, wgt, meta);
}

// Round 7
// 119.440 us; speedup vs baseline: 2.2636x; 1.0012x over previous
//
#include <hip/hip_runtime.h>
#include <hip/hip_bf16.h>
#include <math.h>

#define NE 8
#define DD 1024
#define HH 2048
#define NTOK 1024
#define NSLOT 2048
#define NSLOTP 3072

typedef short short8v __attribute__((ext_vector_type(8)));
typedef float f32x4 __attribute__((ext_vector_type(4)));

static __device__ __forceinline__ unsigned short f2bf(float f) {
  union { __hip_bfloat16 h; unsigned short u; } c;
  c.h = __float2bfloat16(f);
  return c.u;
}

// bank-spread for bf16 [n][64B k-row] tiles: granule position = kb ^ sigma(n)
static __device__ __forceinline__ int sigma(int n) {
  return ((n >> 1) & 3) ^ ((n >> 3) & 1);
}

static __device__ __forceinline__ short8v pk8(const float* q) {
  short8v v;
#pragma unroll
  for (int i = 0; i < 8; ++i) v[i] = (short)f2bf(q[i]);
  return v;
}

// ---------------------------------------------------------------------------
// Router: one wave per token, exact f32, softmax over 8, top-2. [verified]
// ---------------------------------------------------------------------------
__global__ __launch_bounds__(64) void krouter(const float* __restrict__ x,
                                              const float* __restrict__ gw,
                                              int* __restrict__ e_sel,
                                              float* __restrict__ w_sel) {
  int n = blockIdx.x;
  int lane = threadIdx.x;
  const float4* xr = (const float4*)(x + (size_t)n * DD);
  const float4* gr = (const float4*)gw;
  float acc[NE];
#pragma unroll
  for (int e = 0; e < NE; ++e) acc[e] = 0.f;
#pragma unroll
  for (int i = 0; i < 4; ++i) {
    float4 xv = xr[lane + i * 64];
#pragma unroll
    for (int e = 0; e < NE; ++e) {
      float4 gv = gr[e * 256 + lane + i * 64];
      acc[e] += xv.x * gv.x + xv.y * gv.y + xv.z * gv.z + xv.w * gv.w;
    }
  }
#pragma unroll
  for (int e = 0; e < NE; ++e)
#pragma unroll
    for (int off = 32; off > 0; off >>= 1) acc[e] += __shfl_xor(acc[e], off);
  if (lane == 0) {
    float m = acc[0];
#pragma unroll
    for (int e = 1; e < NE; ++e) m = fmaxf(m, acc[e]);
    float p[NE];
    float z = 0.f;
#pragma unroll
    for (int e = 0; e < NE; ++e) { p[e] = expf(acc[e] - m); z += p[e]; }
    float inv = 1.f / z;
    int e1 = 0;
#pragma unroll
    for (int e = 1; e < NE; ++e) if (acc[e] > acc[e1]) e1 = e;
    int e2 = (e1 == 0) ? 1 : 0;
#pragma unroll
    for (int e = 0; e < NE; ++e) if (e != e1 && acc[e] > acc[e2]) e2 = e;
    e_sel[n] = e1;         w_sel[n] = p[e1] * inv;
    e_sel[NTOK + n] = e2;  w_sel[NTOK + n] = p[e2] * inv;
  }
}

// ---------------------------------------------------------------------------
// Build per-expert token lists (segments padded to 128) + compact tile maps.
// meta: [0:8) counts, [8:16) startp, [16] n64, [17] n128,
//       [32:80) t64e, [80:128) t64m, [128:152) t128e, [152:176) t128m
// ---------------------------------------------------------------------------
__global__ __launch_bounds__(256) void kbuild(const int* __restrict__ e_sel,
                                              const float* __restrict__ w_sel,
                                              int* __restrict__ tok,
                                              float* __restrict__ wgt,
                                              int* __restrict__ meta) {
  __shared__ int sc[NE], scur[NE];
  int t = threadIdx.x;
  if (t < NE) sc[t] = 0;
  __syncthreads();
  for (int s = t; s < NSLOTP; s += 256) tok[s] = -1;
  for (int s = t; s < NSLOT; s += 256) atomicAdd(&sc[e_sel[s]], 1);
  __syncthreads();
  if (t == 0) {
    int run = 0, i64 = 0, i128 = 0;
    for (int e = 0; e < NE; ++e) {
      meta[8 + e] = run; scur[e] = run;
      meta[e] = sc[e];
      int nm = (sc[e] + 127) >> 7;
      for (int m = 0; m < nm; ++m) {
        meta[128 + i128] = e; meta[152 + i128] = m; ++i128;
      }
      for (int m = 0; m < 2 * nm; ++m) {
        meta[32 + i64] = e; meta[80 + i64] = m; ++i64;
      }
      run += nm << 7;
    }
    meta[16] = i64; meta[17] = i128;
  }
  __syncthreads();
  for (int s = t; s < NSLOT; s += 256) {
    int e = e_sel[s];
    int pos = atomicAdd(&scur[e], 1);
    tok[pos] = s & (NTOK - 1);
    wgt[pos] = w_sel[s];
  }
}

// ---------------------------------------------------------------------------
// Gather+convert x -> xg[NSLOTP][1024] bf16. Row = 32 chunks of 64B; granule
// g at position g ^ ((row>>1)&3) within chunk. Pad rows zeroed. [verified]
// ---------------------------------------------------------------------------
__global__ __launch_bounds__(256) void kgather(const float* __restrict__ x,
                                               const int* __restrict__ tok,
                                               unsigned short* __restrict__ xg) {
  int tid = threadIdx.x;
  int row = blockIdx.x * 2 + (tid >> 7);
  int g = tid & 127;
  int t = tok[row];
  int pos = (g & 3) ^ ((row >> 1) & 3);
  char* dst = (char*)xg + (size_t)row * 2048 + (g >> 2) * 64 + (pos << 4);
  short8v v = {0, 0, 0, 0, 0, 0, 0, 0};
  if (t >= 0) {
    const float* src = x + (size_t)t * DD + g * 8;
    float q[8];
#pragma unroll
    for (int i = 0; i < 8; ++i) q[i] = src[i];
    v = pk8(q);
  }
  *(short8v*)dst = v;
}

// ---------------------------------------------------------------------------
// GEMM1+3 fused: h = silu(X@w1)*(X@w3). BM=128 BN=64 BK=32, 4 waves 2x2
// (wave-tile 64m x 32n per matrix). A: DIRECT global->reg from xg (L2/L3).
// B: w1/w3 f32 dword loads (coalesced 256B rows, 2-step reg prefetch) -> cvt
// -> conflict-free ds_write_b128 into dbuf [mat][n][64B] sigma layout.
// One barrier per K-step. No async ops; compiler manages all waitcnts.
// ---------------------------------------------------------------------------
__global__ __launch_bounds__(256, 3) void kgemm13(
    const unsigned short* __restrict__ xg, const float* __restrict__ w1,
    const float* __restrict__ w3, unsigned short* __restrict__ hws,
    const int* __restrict__ meta) {
  __shared__ __align__(16) char smem[16384];  // B dbuf: buf*8192 + mat*4096
  char* ldsB = smem;
  int vt = blockIdx.y;
  if (vt >= meta[17]) return;
  int e = meta[128 + vt], mt = meta[152 + vt];
  int n0 = blockIdx.x * 64;
  int abase = meta[8 + e] + mt * 128;
  int tid = threadIdx.x, l = tid & 63, w = tid >> 6;
  int wm = w & 1, wn = w >> 1;

  // B staging: thread covers 8k x 1n of BOTH matrices. n=tid&63, kb=tid>>6.
  int bn = tid & 63, kb = tid >> 6;
  const float* pb1 = w1 + (size_t)e * DD * HH + (size_t)(kb * 8) * HH + n0 + bn;
  const float* pb3 = w3 + (size_t)e * DD * HH + (size_t)(kb * 8) * HH + n0 + bn;
  int wb = bn * 64 + (((kb ^ sigma(bn)) & 3) << 4);

  // A fragment global sources (pos swizzle per xg layout), step adds s*64.
  const char* pa[4];
#pragma unroll
  for (int mf = 0; mf < 4; ++mf) {
    int r = wm * 64 + mf * 16 + (l & 15);
    pa[mf] = (const char*)xg + (size_t)(abase + r) * 2048 +
             ((((l >> 4) ^ (r >> 1)) & 3) << 4);
  }
  // B fragment LDS offsets.
  int boff[2];
#pragma unroll
  for (int nf = 0; nf < 2; ++nf) {
    int n = wn * 32 + nf * 16 + (l & 15);
    boff[nf] = n * 64 + ((((l >> 4) ^ sigma(n)) & 3) << 4);
  }

  f32x4 accg[4][2], accu[4][2];
#pragma unroll
  for (int i = 0; i < 4; ++i)
#pragma unroll
    for (int j = 0; j < 2; ++j) {
      accg[i][j] = (f32x4){0.f, 0.f, 0.f, 0.f};
      accu[i][j] = (f32x4){0.f, 0.f, 0.f, 0.f};
    }

  float q1[2][8], q3[2][8];
  short8v a[4];
  // ---- prologue ----
#pragma unroll
  for (int r = 0; r < 8; ++r) {
    q1[0][r] = pb1[(size_t)r * HH];
    q3[0][r] = pb3[(size_t)r * HH];
    q1[1][r] = pb1[(size_t)(32 + r) * HH];
    q3[1][r] = pb3[(size_t)(32 + r) * HH];
  }
#pragma unroll
  for (int mf = 0; mf < 4; ++mf) a[mf] = *(const short8v*)(pa[mf]);
  *(short8v*)(ldsB + wb) = pk8(q1[0]);
  *(short8v*)(ldsB + 4096 + wb) = pk8(q3[0]);
#pragma unroll
  for (int r = 0; r < 8; ++r) {
    q1[0][r] = pb1[(size_t)(64 + r) * HH];
    q3[0][r] = pb3[(size_t)(64 + r) * HH];
  }
  __syncthreads();

#define STEP13(S, P)                                                           \
  {                                                                            \
    if ((S) < 31) {                                                            \
      char* d = ldsB + (((P) ^ 1) << 13);                                      \
      *(short8v*)(d + wb) = pk8(q1[(P) ^ 1]);                                  \
      *(short8v*)(d + 4096 + wb) = pk8(q3[(P) ^ 1]);                           \
    }                                                                          \
    if ((S) < 29) {                                                            \
      const float* s1 = pb1 + (size_t)((S) + 3) * 32 * HH;                     \
      const float* s3 = pb3 + (size_t)((S) + 3) * 32 * HH;                     \
      _Pragma("unroll") for (int r = 0; r < 8; ++r) {                          \
        q1[(P) ^ 1][r] = s1[(size_t)r * HH];                                   \
        q3[(P) ^ 1][r] = s3[(size_t)r * HH];                                   \
      }                                                                        \
    }                                                                          \
    short8v b1f[2], b3f[2];                                                    \
    _Pragma("unroll") for (int nf = 0; nf < 2; ++nf) {                         \
      b1f[nf] = *(const short8v*)(ldsB + ((P) << 13) + boff[nf]);              \
      b3f[nf] = *(const short8v*)(ldsB + ((P) << 13) + 4096 + boff[nf]);       \
    }                                                                          \
    _Pragma("unroll") for (int nf = 0; nf < 2; ++nf)                           \
        _Pragma("unroll") for (int mf = 0; mf < 4; ++mf) {                     \
      accg[mf][nf] = __builtin_amdgcn_mfma_f32_16x16x32_bf16(                  \
          a[mf], b1f[nf], accg[mf][nf], 0, 0, 0);                              \
      accu[mf][nf] = __builtin_amdgcn_mfma_f32_16x16x32_bf16(                  \
          a[mf], b3f[nf], accu[mf][nf], 0, 0, 0);                              \
    }                                                                          \
    if ((S) < 31) {                                                           \
      _Pragma("unroll") for (int mf = 0; mf < 4; ++mf)                         \
          a[mf] = *(const short8v*)(pa[mf] + ((S) + 1) * 64);                  \
    }                                                                          \
    __syncthreads();                                                           \
  }

  for (int ss = 0; ss < 16; ++ss) {
    int s0 = 2 * ss;
    STEP13(s0, 0);
    STEP13(s0 + 1, 1);
  }
#undef STEP13

  // Epilogue: silu(g)*u -> bf16 -> LDS restage (128x64) -> hws store.
  unsigned short* hl = (unsigned short*)smem;  // 16KB
#pragma unroll
  for (int mf = 0; mf < 4; ++mf)
#pragma unroll
    for (int nf = 0; nf < 2; ++nf)
#pragma unroll
      for (int rr = 0; rr < 4; ++rr) {
        int row = wm * 64 + mf * 16 + ((l >> 4) << 2) + rr;
        int col = wn * 32 + nf * 16 + (l & 15);
        float gv = accg[mf][nf][rr], uv = accu[mf][nf][rr];
        hl[row * 64 + col] = f2bf((gv / (1.f + __expf(-gv))) * uv);
      }
  __syncthreads();
#pragma unroll
  for (int p = 0; p < 4; ++p) {
    int idx = p * 256 + tid;
    int row = idx >> 3, g = idx & 7;
    int dp = abase + row;
    size_t db = (size_t)dp * 4096 + (size_t)n0 * 2 + (g >> 2) * 64 +
                ((size_t)((g & 3) ^ ((dp >> 1) & 3)) << 4);
    *(short8v*)((char*)hws + db) =
        *(const short8v*)((const char*)hl + row * 128 + (g << 4));
  }
}

// ---------------------------------------------------------------------------
// GEMM2: y = h @ w2 (*routing weight), atomic scatter. BM=128 BN=64 BK=32,
// K-split 2, 4 waves 2x2. A direct from hws (global), B staged like kgemm13.
// ---------------------------------------------------------------------------
__global__ __launch_bounds__(256, 4) void kgemm2(
    const unsigned short* __restrict__ hws, const float* __restrict__ w2,
    float* __restrict__ out, const int* __restrict__ tok,
    const float* __restrict__ wgt, const int* __restrict__ meta) {
  __shared__ __align__(16) char smem[8192];  // B dbuf: buf*4096
  char* ldsB = smem;
  int vt = blockIdx.y;
  if (vt >= meta[17]) return;
  int e = meta[128 + vt], mt = meta[152 + vt];
  int n0 = blockIdx.x * 64;
  int kz = blockIdx.z;
  int mbase = meta[8 + e] + mt * 128;
  int rem = meta[e] - mt * 128;
  int tid = threadIdx.x, l = tid & 63, w = tid >> 6;
  int wm = w & 1, wn = w >> 1;

  int bn = tid & 63, kb = tid >> 6;
  const float* pb = w2 + (size_t)e * HH * DD +
                    (size_t)(kz * 1024 + kb * 8) * DD + n0 + bn;
  int wb = bn * 64 + (((kb ^ sigma(bn)) & 3) << 4);

  const char* pa[4];
#pragma unroll
  for (int mf = 0; mf < 4; ++mf) {
    int r = wm * 64 + mf * 16 + (l & 15);
    pa[mf] = (const char*)hws + (size_t)(mbase + r) * 4096 + kz * 2048 +
             ((((l >> 4) ^ (r >> 1)) & 3) << 4);
  }
  int boff[2];
#pragma unroll
  for (int nf = 0; nf < 2; ++nf) {
    int n = wn * 32 + nf * 16 + (l & 15);
    boff[nf] = n * 64 + ((((l >> 4) ^ sigma(n)) & 3) << 4);
  }

  f32x4 acc[4][2];
#pragma unroll
  for (int i = 0; i < 4; ++i)
#pragma unroll
    for (int j = 0; j < 2; ++j) acc[i][j] = (f32x4){0.f, 0.f, 0.f, 0.f};

  float q[2][8];
  short8v a[4];
#pragma unroll
  for (int r = 0; r < 8; ++r) {
    q[0][r] = pb[(size_t)r * DD];
    q[1][r] = pb[(size_t)(32 + r) * DD];
  }
#pragma unroll
  for (int mf = 0; mf < 4; ++mf) a[mf] = *(const short8v*)(pa[mf]);
  *(short8v*)(ldsB + wb) = pk8(q[0]);
#pragma unroll
  for (int r = 0; r < 8; ++r) q[0][r] = pb[(size_t)(64 + r) * DD];
  __syncthreads();

#define STEP2(S, P)                                                            \
  {                                                                            \
    if ((S) < 31) {                                                            \
      *(short8v*)(ldsB + (((P) ^ 1) << 12) + wb) = pk8(q[(P) ^ 1]);            \
    }                                                                          \
    if ((S) < 29) {                                                            \
      const float* sp = pb + (size_t)((S) + 3) * 32 * DD;                      \
      _Pragma("unroll") for (int r = 0; r < 8; ++r)                            \
          q[(P) ^ 1][r] = sp[(size_t)r * DD];                                  \
    }                                                                          \
    short8v bf[2];                                                             \
    _Pragma("unroll") for (int nf = 0; nf < 2; ++nf)                           \
        bf[nf] = *(const short8v*)(ldsB + ((P) << 12) + boff[nf]);             \
    _Pragma("unroll") for (int nf = 0; nf < 2; ++nf)                           \
        _Pragma("unroll") for (int mf = 0; mf < 4; ++mf)                       \
            acc[mf][nf] = __builtin_amdgcn_mfma_f32_16x16x32_bf16(             \
                a[mf], bf[nf], acc[mf][nf], 0, 0, 0);                          \
    if ((S) < 31) {                                                           \
      _Pragma("unroll") for (int mf = 0; mf < 4; ++mf)                         \
          a[mf] = *(const short8v*)(pa[mf] + ((S) + 1) * 64);                  \
    }                                                                          \
    __syncthreads();                                                           \
  }

  for (int ss = 0; ss < 16; ++ss) {
    int s0 = 2 * ss;
    STEP2(s0, 0);
    STEP2(s0 + 1, 1);
  }
#undef STEP2

#pragma unroll
  for (int mf = 0; mf < 4; ++mf)
#pragma unroll
    for (int rr = 0; rr < 4; ++rr) {
      int row = wm * 64 + mf * 16 + ((l >> 4) << 2) + rr;
      if (row < rem) {
        int t = tok[mbase + row];
        float wt = wgt[mbase + row];
#pragma unroll
        for (int nf = 0; nf < 2; ++nf)
          atomicAdd(out + (size_t)t * DD + n0 + wn * 32 + nf * 16 + (l & 15),
                    wt * acc[mf][nf][rr]);
      }
    }
}

// ---------------------------------------------------------------------------
extern "C" void kernel_launch(void* const* d_in, const int* in_sizes, int n_in,
                              void* d_out, int out_size, void* d_ws, size_t ws_size,
                              hipStream_t stream) {
  const float* x  = (const float*)d_in[0];
  const float* gw = (const float*)d_in[1];
  const float* w1 = (const float*)d_in[2];
  const float* w2 = (const float*)d_in[3];
  const float* w3 = (const float*)d_in[4];
  float* out = (float*)d_out;
  char* ws = (char*)d_ws;
  const size_t MB = 1024 * 1024;
  if (ws_size < 24 * MB) return;

  unsigned short* xg  = (unsigned short*)(ws);            // 6MB
  unsigned short* hws = (unsigned short*)(ws + 6 * MB);   // 12MB
  char* mb = ws + 20 * MB;
  int*   e_sel  = (int*)mb;
  float* w_sel  = (float*)(mb + 8192);
  int*   tok    = (int*)(mb + 16384);
  float* wgt    = (float*)(mb + 16384 + 12288);
  int*   meta   = (int*)(mb + 16384 + 24576);

  hipMemsetAsync(out, 0, (size_t)out_size * sizeof(float), stream);
  krouter<<<dim3(NTOK), 64, 0, stream>>>(x, gw, e_sel, w_sel);
  kbuild<<<1, 256, 0, stream>>>(e_sel, w_sel, tok, wgt, meta);
  kgather<<<dim3(NSLOTP / 2), 256, 0, stream>>>(x, tok, xg);
  kgemm13<<<dim3(32, 24), 256, 0, stream>>>(xg, w1, w3, hws, meta);
  kgemm2<<<dim3(16, 24, 2), 256, 0, stream>>>(hws, w2, out, tok, wgt, meta);
}